// Round 1
// baseline (492.548 us; speedup 1.0000x reference)
//
#include <hip/hip_runtime.h>
#include <math.h>

#define N_USERS 8192
#define N_ITEMS 4096
#define BATCH   8192

// ---------------------------------------------------------------------------
// K1: per-user fixed bias: ub[u] = cnt>0 ? row_sum/max(cnt,1) : 0
// One block per user row. Row = 4096 floats, read as float4.
// ---------------------------------------------------------------------------
__global__ __launch_bounds__(256) void k_ubfix(const float* __restrict__ R,
                                               float* __restrict__ ub) {
    const int u = blockIdx.x;
    const float4* row4 = (const float4*)(R + (size_t)u * N_ITEMS);
    float s = 0.f, c = 0.f;
    for (int i = threadIdx.x; i < N_ITEMS / 4; i += 256) {
        float4 v = row4[i];
        s += v.x + v.y + v.z + v.w;
        c += (v.x != 0.f) + (v.y != 0.f) + (v.z != 0.f) + (v.w != 0.f);
    }
    // wave (64-lane) reduce, then 4-wave LDS reduce
    for (int off = 32; off; off >>= 1) {
        s += __shfl_down(s, off);
        c += __shfl_down(c, off);
    }
    __shared__ float sa[4], sc[4];
    const int lane = threadIdx.x & 63, w = threadIdx.x >> 6;
    if (lane == 0) { sa[w] = s; sc[w] = c; }
    __syncthreads();
    if (threadIdx.x == 0) {
        float rs = sa[0] + sa[1] + sa[2] + sa[3];
        float cnt = sc[0] + sc[1] + sc[2] + sc[3];
        ub[u] = (cnt > 0.f) ? rs / fmaxf(cnt, 1.f) : 0.f;
    }
}

// ---------------------------------------------------------------------------
// K2: AT[j][u] = R[u][j] - ub[u]   (64x64 LDS-tiled transpose, float4 I/O)
// block (16,16); grid (N_ITEMS/64, N_USERS/64)
// ---------------------------------------------------------------------------
__global__ __launch_bounds__(256) void k_transpose(const float* __restrict__ R,
                                                   const float* __restrict__ ub,
                                                   float* __restrict__ AT) {
    __shared__ float lds[64][65];
    const int colBase = blockIdx.x * 64;   // item dim
    const int rowBase = blockIdx.y * 64;   // user dim
    const int tx = threadIdx.x, ty = threadIdx.y;
    const int x4 = tx * 4;

    // load 64 rows x 64 cols, coalesced along item dim
    #pragma unroll
    for (int k = 0; k < 4; ++k) {
        const int y = ty + 16 * k;
        float4 v = *(const float4*)(R + (size_t)(rowBase + y) * N_ITEMS + colBase + x4);
        lds[y][x4 + 0] = v.x;
        lds[y][x4 + 1] = v.y;
        lds[y][x4 + 2] = v.z;
        lds[y][x4 + 3] = v.w;
    }
    __syncthreads();

    // per-thread user-bias values (depend on tx only)
    const float u0 = ub[rowBase + x4 + 0];
    const float u1 = ub[rowBase + x4 + 1];
    const float u2 = ub[rowBase + x4 + 2];
    const float u3 = ub[rowBase + x4 + 3];

    // store transposed, coalesced along user dim
    #pragma unroll
    for (int k = 0; k < 4; ++k) {
        const int y = ty + 16 * k;        // local item index
        float4 w;
        w.x = lds[x4 + 0][y] - u0;
        w.y = lds[x4 + 1][y] - u1;
        w.z = lds[x4 + 2][y] - u2;
        w.w = lds[x4 + 3][y] - u3;
        *(float4*)(AT + (size_t)(colBase + y) * N_USERS + rowBase + x4) = w;
    }
}

// ---------------------------------------------------------------------------
// K3: one block per batch element: dot(S[user[b]], AT[item[b]]) + biases,
// sigmoid * 5
// ---------------------------------------------------------------------------
__global__ __launch_bounds__(256) void k_main(const float* __restrict__ S,
                                              const float* __restrict__ AT,
                                              const int* __restrict__ user,
                                              const int* __restrict__ item,
                                              const float* __restrict__ ubias,
                                              const float* __restrict__ ibias,
                                              const float* __restrict__ gbias,
                                              float* __restrict__ out) {
    const int b = blockIdx.x;
    const int su = user[b];
    const int j  = item[b];
    const float4* srow = (const float4*)(S  + (size_t)su * N_USERS);
    const float4* arow = (const float4*)(AT + (size_t)j  * N_USERS);
    float acc = 0.f;
    for (int i = threadIdx.x; i < N_USERS / 4; i += 256) {
        float4 a = srow[i];
        float4 r = arow[i];
        acc += a.x * r.x + a.y * r.y + a.z * r.z + a.w * r.w;
    }
    for (int off = 32; off; off >>= 1) acc += __shfl_down(acc, off);
    __shared__ float sa[4];
    const int lane = threadIdx.x & 63, w = threadIdx.x >> 6;
    if (lane == 0) sa[w] = acc;
    __syncthreads();
    if (threadIdx.x == 0) {
        float score = sa[0] + sa[1] + sa[2] + sa[3]
                    + ubias[su] + ibias[j] + gbias[0];
        out[b] = 5.f / (1.f + expf(-score));
    }
}

// ---------------------------------------------------------------------------
// Fallback (ws too small for the transpose): direct strided column gather.
// Correct but slow; only used if ws_size is insufficient.
// ---------------------------------------------------------------------------
__global__ __launch_bounds__(256) void k_direct(const float* __restrict__ S,
                                                const float* __restrict__ R,
                                                const float* __restrict__ ub,
                                                const int* __restrict__ user,
                                                const int* __restrict__ item,
                                                const float* __restrict__ ubias,
                                                const float* __restrict__ ibias,
                                                const float* __restrict__ gbias,
                                                float* __restrict__ out) {
    const int b = blockIdx.x;
    const int su = user[b];
    const int j  = item[b];
    const float* srow = S + (size_t)su * N_USERS;
    float acc = 0.f;
    for (int u = threadIdx.x; u < N_USERS; u += 256) {
        acc += srow[u] * (R[(size_t)u * N_ITEMS + j] - ub[u]);
    }
    for (int off = 32; off; off >>= 1) acc += __shfl_down(acc, off);
    __shared__ float sa[4];
    const int lane = threadIdx.x & 63, w = threadIdx.x >> 6;
    if (lane == 0) sa[w] = acc;
    __syncthreads();
    if (threadIdx.x == 0) {
        float score = sa[0] + sa[1] + sa[2] + sa[3]
                    + ubias[su] + ibias[j] + gbias[0];
        out[b] = 5.f / (1.f + expf(-score));
    }
}

extern "C" void kernel_launch(void* const* d_in, const int* in_sizes, int n_in,
                              void* d_out, int out_size, void* d_ws, size_t ws_size,
                              hipStream_t stream) {
    const int*   user  = (const int*)d_in[0];
    const int*   item  = (const int*)d_in[1];
    const float* R     = (const float*)d_in[2];   // rating_mtx  [N_USERS][N_ITEMS]
    const float* S     = (const float*)d_in[3];   // user_similarity [N_USERS][N_USERS]
    const float* ubias = (const float*)d_in[4];
    const float* ibias = (const float*)d_in[5];
    const float* gbias = (const float*)d_in[6];
    float* out = (float*)d_out;

    // ws layout: [0, 32KB) = ub[N_USERS]; [64KB, 64KB+134MB) = AT[N_ITEMS][N_USERS]
    float* ub = (float*)d_ws;
    float* AT = (float*)((char*)d_ws + 65536);
    const size_t need = 65536 + (size_t)N_ITEMS * N_USERS * sizeof(float);

    k_ubfix<<<N_USERS, 256, 0, stream>>>(R, ub);

    if (ws_size >= need) {
        dim3 tgrid(N_ITEMS / 64, N_USERS / 64);
        dim3 tblk(16, 16);
        k_transpose<<<tgrid, tblk, 0, stream>>>(R, ub, AT);
        k_main<<<BATCH, 256, 0, stream>>>(S, AT, user, item, ubias, ibias, gbias, out);
    } else {
        k_direct<<<BATCH, 256, 0, stream>>>(S, R, ub, user, item, ubias, ibias, gbias, out);
    }
}

// Round 3
// 470.757 us; speedup vs baseline: 1.0463x; 1.0463x over previous
//
#include <hip/hip_runtime.h>
#include <math.h>

#define N_USERS 8192
#define N_ITEMS 4096
#define BATCH   8192

// bf16 via raw bits (header-version independent; we control both sides).
__device__ __forceinline__ unsigned short f32_to_bf16_rne(float f) {
    union { float f; unsigned int u; } cvt;
    cvt.f = f;
    unsigned int u = cvt.u;
    u += 0x7fffu + ((u >> 16) & 1u);     // round to nearest even
    return (unsigned short)(u >> 16);
}
__device__ __forceinline__ float bf16_bits_to_f32(unsigned int h) {
    union { unsigned int u; float f; } cvt;
    cvt.u = h << 16;
    return cvt.f;
}

// ---------------------------------------------------------------------------
// K1: ub[u] = cnt>0 ? row_sum/max(cnt,1) : 0.  One WAVE per user row.
// Row = 4096 floats = 1024 float4; 64 lanes x 16 iters. Grid = 2048 x 256thr.
// ---------------------------------------------------------------------------
__global__ __launch_bounds__(256) void k_ubfix(const float* __restrict__ R,
                                               float* __restrict__ ub) {
    const int wave = threadIdx.x >> 6;
    const int lane = threadIdx.x & 63;
    const int u = blockIdx.x * 4 + wave;
    const float4* row4 = (const float4*)(R + (size_t)u * N_ITEMS);
    float s = 0.f, c = 0.f;
    #pragma unroll
    for (int i = 0; i < 16; ++i) {
        float4 v = row4[i * 64 + lane];
        s += v.x + v.y + v.z + v.w;
        c += (v.x != 0.f) + (v.y != 0.f) + (v.z != 0.f) + (v.w != 0.f);
    }
    #pragma unroll
    for (int off = 32; off; off >>= 1) {
        s += __shfl_down(s, off);
        c += __shfl_down(c, off);
    }
    if (lane == 0)
        ub[u] = (c > 0.f) ? s / fmaxf(c, 1.f) : 0.f;
}

// ---------------------------------------------------------------------------
// K2: AT[j][u] = bf16(R[u][j] - ub[u])   64x64 LDS-tiled transpose.
// block (16,16); grid (N_ITEMS/64, N_USERS/64). Reads f32, writes bf16.
// ---------------------------------------------------------------------------
__global__ __launch_bounds__(256) void k_transpose(const float* __restrict__ R,
                                                   const float* __restrict__ ub,
                                                   unsigned short* __restrict__ AT) {
    __shared__ float lds[64][65];
    const int colBase = blockIdx.x * 64;   // item dim
    const int rowBase = blockIdx.y * 64;   // user dim
    const int tx = threadIdx.x, ty = threadIdx.y;
    const int x4 = tx * 4;

    // load 64 user-rows x 64 item-cols, coalesced along item dim
    #pragma unroll
    for (int k = 0; k < 4; ++k) {
        const int y = ty + 16 * k;
        float4 v = *(const float4*)(R + (size_t)(rowBase + y) * N_ITEMS + colBase + x4);
        lds[y][x4 + 0] = v.x;
        lds[y][x4 + 1] = v.y;
        lds[y][x4 + 2] = v.z;
        lds[y][x4 + 3] = v.w;
    }
    __syncthreads();

    const float u0 = ub[rowBase + x4 + 0];
    const float u1 = ub[rowBase + x4 + 1];
    const float u2 = ub[rowBase + x4 + 2];
    const float u3 = ub[rowBase + x4 + 3];

    // store transposed: 4 consecutive users as bf16x4 (8 B/thread, 128 B/16thr)
    #pragma unroll
    for (int k = 0; k < 4; ++k) {
        const int y = ty + 16 * k;        // local item index
        ushort4 w;
        w.x = f32_to_bf16_rne(lds[x4 + 0][y] - u0);
        w.y = f32_to_bf16_rne(lds[x4 + 1][y] - u1);
        w.z = f32_to_bf16_rne(lds[x4 + 2][y] - u2);
        w.w = f32_to_bf16_rne(lds[x4 + 3][y] - u3);
        *(ushort4*)(AT + (size_t)(colBase + y) * N_USERS + rowBase + x4) = w;
    }
}

// ---------------------------------------------------------------------------
// K3: one WAVE per batch element.  dot(S[user[b]] (f32), AT[item[b]] (bf16))
// + biases, sigmoid*5.  64 lanes x 16 iters x 8 users/lane/iter.
// Grid = 2048 x 256thr.
// ---------------------------------------------------------------------------
__global__ __launch_bounds__(256) void k_main(const float* __restrict__ S,
                                              const unsigned short* __restrict__ AT,
                                              const int* __restrict__ user,
                                              const int* __restrict__ item,
                                              const float* __restrict__ ubias,
                                              const float* __restrict__ ibias,
                                              const float* __restrict__ gbias,
                                              float* __restrict__ out) {
    const int wave = threadIdx.x >> 6;
    const int lane = threadIdx.x & 63;
    const int b = blockIdx.x * 4 + wave;
    const int su = user[b];
    const int j  = item[b];
    const float4* srow = (const float4*)(S + (size_t)su * N_USERS);
    const uint4*  arow = (const uint4*)(AT + (size_t)j * N_USERS);

    float acc = 0.f;
    #pragma unroll 4
    for (int i = 0; i < 16; ++i) {
        const int idx = i * 64 + lane;       // unit = 8 users
        uint4  a  = arow[idx];               // 8 bf16
        float4 s0 = srow[idx * 2 + 0];
        float4 s1 = srow[idx * 2 + 1];
        acc += s0.x * bf16_bits_to_f32(a.x & 0xffffu);
        acc += s0.y * bf16_bits_to_f32(a.x >> 16);
        acc += s0.z * bf16_bits_to_f32(a.y & 0xffffu);
        acc += s0.w * bf16_bits_to_f32(a.y >> 16);
        acc += s1.x * bf16_bits_to_f32(a.z & 0xffffu);
        acc += s1.y * bf16_bits_to_f32(a.z >> 16);
        acc += s1.z * bf16_bits_to_f32(a.w & 0xffffu);
        acc += s1.w * bf16_bits_to_f32(a.w >> 16);
    }
    #pragma unroll
    for (int off = 32; off; off >>= 1) acc += __shfl_down(acc, off);

    if (lane == 0) {
        float score = acc + ubias[su] + ibias[j] + gbias[0];
        out[b] = 5.f / (1.f + expf(-score));
    }
}

// ---------------------------------------------------------------------------
// Fallback (ws too small): direct strided column gather. Correct but slow.
// ---------------------------------------------------------------------------
__global__ __launch_bounds__(256) void k_direct(const float* __restrict__ S,
                                                const float* __restrict__ R,
                                                const float* __restrict__ ub,
                                                const int* __restrict__ user,
                                                const int* __restrict__ item,
                                                const float* __restrict__ ubias,
                                                const float* __restrict__ ibias,
                                                const float* __restrict__ gbias,
                                                float* __restrict__ out) {
    const int b = blockIdx.x;
    const int su = user[b];
    const int j  = item[b];
    const float* srow = S + (size_t)su * N_USERS;
    float acc = 0.f;
    for (int u = threadIdx.x; u < N_USERS; u += 256) {
        acc += srow[u] * (R[(size_t)u * N_ITEMS + j] - ub[u]);
    }
    for (int off = 32; off; off >>= 1) acc += __shfl_down(acc, off);
    __shared__ float sa[4];
    const int lane = threadIdx.x & 63, w = threadIdx.x >> 6;
    if (lane == 0) sa[w] = acc;
    __syncthreads();
    if (threadIdx.x == 0) {
        float score = sa[0] + sa[1] + sa[2] + sa[3]
                    + ubias[su] + ibias[j] + gbias[0];
        out[b] = 5.f / (1.f + expf(-score));
    }
}

extern "C" void kernel_launch(void* const* d_in, const int* in_sizes, int n_in,
                              void* d_out, int out_size, void* d_ws, size_t ws_size,
                              hipStream_t stream) {
    const int*   user  = (const int*)d_in[0];
    const int*   item  = (const int*)d_in[1];
    const float* R     = (const float*)d_in[2];   // [N_USERS][N_ITEMS] f32
    const float* S     = (const float*)d_in[3];   // [N_USERS][N_USERS] f32
    const float* ubias = (const float*)d_in[4];
    const float* ibias = (const float*)d_in[5];
    const float* gbias = (const float*)d_in[6];
    float* out = (float*)d_out;

    // ws layout: [0, 32KB) ub[N_USERS] f32; [64KB, ...) AT[N_ITEMS][N_USERS] bf16
    float* ub = (float*)d_ws;
    unsigned short* AT = (unsigned short*)((char*)d_ws + 65536);
    const size_t need = 65536 + (size_t)N_ITEMS * N_USERS * sizeof(unsigned short);

    k_ubfix<<<N_USERS / 4, 256, 0, stream>>>(R, ub);

    if (ws_size >= need) {
        dim3 tgrid(N_ITEMS / 64, N_USERS / 64);
        dim3 tblk(16, 16);
        k_transpose<<<tgrid, tblk, 0, stream>>>(R, ub, AT);
        k_main<<<BATCH / 4, 256, 0, stream>>>(S, AT, user, item, ubias, ibias, gbias, out);
    } else {
        k_direct<<<BATCH, 256, 0, stream>>>(S, R, ub, user, item, ubias, ibias, gbias, out);
    }
}

// Round 4
// 469.166 us; speedup vs baseline: 1.0498x; 1.0034x over previous
//
#include <hip/hip_runtime.h>
#include <math.h>

#define N_USERS 8192
#define N_ITEMS 4096
#define BATCH   8192
#define NTILE_I (N_ITEMS / 64)   // 64 item tiles per user stripe

// ---------------------------------------------------------------------------
// K_A: fused transpose + per-row partial sums.
//   AT[j][u] = (uint8)R[u][j]            (exact: R in {0..5})
//   psum[bx][u] = sum of R[u][ colBase .. colBase+63 ]
//   pcnt[bx][u] = nonzero count of same
// grid (NTILE_I, N_USERS/64), block (16,16).
// ---------------------------------------------------------------------------
__global__ __launch_bounds__(256) void k_trans(const float* __restrict__ R,
                                               unsigned char* __restrict__ AT,
                                               float* __restrict__ psum,
                                               float* __restrict__ pcnt) {
    __shared__ float lds[64][65];
    const int colBase = blockIdx.x * 64;   // item dim
    const int rowBase = blockIdx.y * 64;   // user dim
    const int tx = threadIdx.x, ty = threadIdx.y;
    const int x4 = tx * 4;

    float s[4], c[4];
    #pragma unroll
    for (int k = 0; k < 4; ++k) {
        const int y = ty + 16 * k;
        float4 v = *(const float4*)(R + (size_t)(rowBase + y) * N_ITEMS + colBase + x4);
        lds[y][x4 + 0] = v.x;
        lds[y][x4 + 1] = v.y;
        lds[y][x4 + 2] = v.z;
        lds[y][x4 + 3] = v.w;
        s[k] = v.x + v.y + v.z + v.w;
        c[k] = (v.x != 0.f) + (v.y != 0.f) + (v.z != 0.f) + (v.w != 0.f);
    }
    // reduce the 16 tx-lanes of each (ty,k) row group (lane = tx + 16*ty)
    #pragma unroll
    for (int k = 0; k < 4; ++k) {
        #pragma unroll
        for (int off = 8; off; off >>= 1) {
            s[k] += __shfl_down(s[k], off, 16);
            c[k] += __shfl_down(c[k], off, 16);
        }
    }
    if (tx == 0) {
        #pragma unroll
        for (int k = 0; k < 4; ++k) {
            const int u = rowBase + ty + 16 * k;
            psum[(size_t)blockIdx.x * N_USERS + u] = s[k];
            pcnt[(size_t)blockIdx.x * N_USERS + u] = c[k];
        }
    }
    __syncthreads();

    // store phase: 64 item-rows x 8 uchar8-chunks = 512 stores, 2 per thread
    const int tid = ty * 16 + tx;
    #pragma unroll
    for (int ss = 0; ss < 2; ++ss) {
        const int idx = ss * 256 + tid;
        const int il = idx >> 3;          // local item row 0..63
        const int ch = idx & 7;           // user chunk (8 users)
        unsigned long long w = 0;
        #pragma unroll
        for (int e = 0; e < 8; ++e) {
            w |= (unsigned long long)(unsigned char)(int)lds[ch * 8 + e][il] << (8 * e);
        }
        *(unsigned long long*)(AT + (size_t)(colBase + il) * N_USERS + rowBase + ch * 8) = w;
    }
}

// ---------------------------------------------------------------------------
// K_fin: ub[u] = cnt>0 ? sum/max(cnt,1) : 0   (reduce 64 tile-partials)
// grid N_USERS/256.
// ---------------------------------------------------------------------------
__global__ __launch_bounds__(256) void k_fin(const float* __restrict__ psum,
                                             const float* __restrict__ pcnt,
                                             float* __restrict__ ub) {
    const int u = blockIdx.x * 256 + threadIdx.x;
    float s = 0.f, c = 0.f;
    #pragma unroll
    for (int t = 0; t < NTILE_I; ++t) {
        s += psum[(size_t)t * N_USERS + u];
        c += pcnt[(size_t)t * N_USERS + u];
    }
    ub[u] = (c > 0.f) ? s / fmaxf(c, 1.f) : 0.f;
}

// ---------------------------------------------------------------------------
// K_B: one WAVE per batch element.
//   out[b] = sigmoid( dot(S[user[b]], (float)AT[item[b]] - ub) + biases ) * 5
// Grid BATCH/4 x 256thr. Per iter/lane: 8 users = 8 B AT + 32 B S + 32 B ub(L2).
// ---------------------------------------------------------------------------
__global__ __launch_bounds__(256) void k_main(const float* __restrict__ S,
                                              const unsigned char* __restrict__ AT,
                                              const float* __restrict__ ub,
                                              const int* __restrict__ user,
                                              const int* __restrict__ item,
                                              const float* __restrict__ ubias,
                                              const float* __restrict__ ibias,
                                              const float* __restrict__ gbias,
                                              float* __restrict__ out) {
    const int wave = threadIdx.x >> 6;
    const int lane = threadIdx.x & 63;
    const int b = blockIdx.x * 4 + wave;
    const int su = user[b];
    const int j  = item[b];
    const float4* srow  = (const float4*)(S + (size_t)su * N_USERS);
    const float4* ubrow = (const float4*)ub;
    const uint2*  arow  = (const uint2*)(AT + (size_t)j * N_USERS);

    float acc = 0.f;
    #pragma unroll 4
    for (int i = 0; i < 16; ++i) {
        const int idx = i * 64 + lane;       // unit = 8 users
        uint2  a  = arow[idx];
        float4 s0 = srow[2 * idx + 0];
        float4 s1 = srow[2 * idx + 1];
        float4 u0 = ubrow[2 * idx + 0];
        float4 u1 = ubrow[2 * idx + 1];
        acc += s0.x * ((float)( a.x        & 0xffu) - u0.x);
        acc += s0.y * ((float)((a.x >>  8) & 0xffu) - u0.y);
        acc += s0.z * ((float)((a.x >> 16) & 0xffu) - u0.z);
        acc += s0.w * ((float)( a.x >> 24         ) - u0.w);
        acc += s1.x * ((float)( a.y        & 0xffu) - u1.x);
        acc += s1.y * ((float)((a.y >>  8) & 0xffu) - u1.y);
        acc += s1.z * ((float)((a.y >> 16) & 0xffu) - u1.z);
        acc += s1.w * ((float)( a.y >> 24         ) - u1.w);
    }
    #pragma unroll
    for (int off = 32; off; off >>= 1) acc += __shfl_down(acc, off);

    if (lane == 0) {
        float score = acc + ubias[su] + ibias[j] + gbias[0];
        out[b] = 5.f / (1.f + expf(-score));
    }
}

// ---------------------------------------------------------------------------
// Fallback path (ws too small): original 3-pass f32 scheme.
// ---------------------------------------------------------------------------
__global__ __launch_bounds__(256) void k_ubfix(const float* __restrict__ R,
                                               float* __restrict__ ub) {
    const int wave = threadIdx.x >> 6;
    const int lane = threadIdx.x & 63;
    const int u = blockIdx.x * 4 + wave;
    const float4* row4 = (const float4*)(R + (size_t)u * N_ITEMS);
    float s = 0.f, c = 0.f;
    #pragma unroll
    for (int i = 0; i < 16; ++i) {
        float4 v = row4[i * 64 + lane];
        s += v.x + v.y + v.z + v.w;
        c += (v.x != 0.f) + (v.y != 0.f) + (v.z != 0.f) + (v.w != 0.f);
    }
    #pragma unroll
    for (int off = 32; off; off >>= 1) {
        s += __shfl_down(s, off);
        c += __shfl_down(c, off);
    }
    if (lane == 0)
        ub[u] = (c > 0.f) ? s / fmaxf(c, 1.f) : 0.f;
}

__global__ __launch_bounds__(256) void k_direct(const float* __restrict__ S,
                                                const float* __restrict__ R,
                                                const float* __restrict__ ub,
                                                const int* __restrict__ user,
                                                const int* __restrict__ item,
                                                const float* __restrict__ ubias,
                                                const float* __restrict__ ibias,
                                                const float* __restrict__ gbias,
                                                float* __restrict__ out) {
    const int b = blockIdx.x;
    const int su = user[b];
    const int j  = item[b];
    const float* srow = S + (size_t)su * N_USERS;
    float acc = 0.f;
    for (int u = threadIdx.x; u < N_USERS; u += 256) {
        acc += srow[u] * (R[(size_t)u * N_ITEMS + j] - ub[u]);
    }
    for (int off = 32; off; off >>= 1) acc += __shfl_down(acc, off);
    __shared__ float sa[4];
    const int lane = threadIdx.x & 63, w = threadIdx.x >> 6;
    if (lane == 0) sa[w] = acc;
    __syncthreads();
    if (threadIdx.x == 0) {
        float score = sa[0] + sa[1] + sa[2] + sa[3]
                    + ubias[su] + ibias[j] + gbias[0];
        out[b] = 5.f / (1.f + expf(-score));
    }
}

extern "C" void kernel_launch(void* const* d_in, const int* in_sizes, int n_in,
                              void* d_out, int out_size, void* d_ws, size_t ws_size,
                              hipStream_t stream) {
    const int*   user  = (const int*)d_in[0];
    const int*   item  = (const int*)d_in[1];
    const float* R     = (const float*)d_in[2];   // [N_USERS][N_ITEMS] f32
    const float* S     = (const float*)d_in[3];   // [N_USERS][N_USERS] f32
    const float* ubias = (const float*)d_in[4];
    const float* ibias = (const float*)d_in[5];
    const float* gbias = (const float*)d_in[6];
    float* out = (float*)d_out;

    // ws layout:
    //   [0, 32KB)            ub[N_USERS] f32
    //   [64KB, 64KB+2MB)     psum[NTILE_I][N_USERS] f32
    //   [64KB+2MB, +2MB)     pcnt[NTILE_I][N_USERS] f32
    //   [8MB, 8MB+33.5MB)    AT[N_ITEMS][N_USERS] uint8
    float* ub   = (float*)d_ws;
    float* psum = (float*)((char*)d_ws + (64u << 10));
    float* pcnt = (float*)((char*)d_ws + (64u << 10) + ((size_t)NTILE_I * N_USERS * 4));
    unsigned char* AT = (unsigned char*)((char*)d_ws + (8u << 20));
    const size_t need = (8u << 20) + (size_t)N_ITEMS * N_USERS;

    if (ws_size >= need) {
        dim3 tgrid(NTILE_I, N_USERS / 64);
        dim3 tblk(16, 16);
        k_trans<<<tgrid, tblk, 0, stream>>>(R, AT, psum, pcnt);
        k_fin<<<N_USERS / 256, 256, 0, stream>>>(psum, pcnt, ub);
        k_main<<<BATCH / 4, 256, 0, stream>>>(S, AT, ub, user, item, ubias, ibias, gbias, out);
    } else {
        k_ubfix<<<N_USERS / 4, 256, 0, stream>>>(R, ub);
        k_direct<<<BATCH, 256, 0, stream>>>(S, R, ub, user, item, ubias, ibias, gbias, out);
    }
}